// Round 17
// baseline (260.311 us; speedup 1.0000x reference)
//
#include <hip/hip_runtime.h>
#include <math.h>

#define B_   8
#define F_   4
#define S_   512
#define D_   256
#define H_   8
#define DK_  32
#define DV_  32
#define NBF  32                 // B*F
#define NROWS (NBF * S_)        // 16384
#define NG   (NBF * H_)         // 256 (b,f,h) groups
#define LN_EPS 1e-5f

typedef __attribute__((ext_vector_type(8))) short bf16x8;
typedef __attribute__((ext_vector_type(4))) float f32x4;
typedef __attribute__((ext_vector_type(8))) unsigned short u16x8;

__device__ __forceinline__ short f2bf(float f) {
    union { float f; unsigned u; } v; v.f = f;
    unsigned u = v.u;
    u += 0x7FFFu + ((u >> 16) & 1u);   // round-to-nearest-even
    return (short)(u >> 16);
}

__device__ __forceinline__ bf16x8 pack8(float4 a, float4 b) {
    bf16x8 r;
    r[0] = f2bf(a.x); r[1] = f2bf(a.y); r[2] = f2bf(a.z); r[3] = f2bf(a.w);
    r[4] = f2bf(b.x); r[5] = f2bf(b.y); r[6] = f2bf(b.z); r[7] = f2bf(b.w);
    return r;
}

union BFU { u16x8 u; bf16x8 b; };

// ---------------------------------------------------------------------------
// Kernel 0 (r10-proven 4-mat): pack Wq,Wk,Wv,Wfc into MFMA B-fragment order.
// ---------------------------------------------------------------------------
__global__ __launch_bounds__(64) void wpack_kernel(
    const float* __restrict__ Wq, const float* __restrict__ Wk,
    const float* __restrict__ Wv, const float* __restrict__ Wfc,
    unsigned short* __restrict__ Wp)
{
    const int bid  = blockIdx.x;           // (wsel*8+ks)*16+ct, 512 blocks
    const int ct   = bid & 15;
    const int ks   = (bid >> 4) & 7;
    const int wsel = bid >> 7;
    const float* W = (wsel == 0) ? Wq : (wsel == 1) ? Wk : (wsel == 2) ? Wv : Wfc;
    const int lane = threadIdx.x;
    const int lr = lane & 15, lg = lane >> 4;
    u16x8 t;
#pragma unroll
    for (int j = 0; j < 8; ++j)
        t[j] = (unsigned short)f2bf(W[(ks * 32 + lg * 8 + j) * 256 + ct * 16 + lr]);
    *(u16x8*)(Wp + ((size_t)bid * 64 + lane) * 8) = t;
}

// ---------------------------------------------------------------------------
// Kernel 1 (r16 + v-bf16): q/k/v all written bf16 (rounding moved from each
// consumer to the producer — numerically identical).
// ---------------------------------------------------------------------------
__global__ __launch_bounds__(256) void qkv_kernel(
    const float* __restrict__ x, const unsigned short* __restrict__ Wp,
    unsigned short* __restrict__ qb, unsigned short* __restrict__ kb,
    unsigned short* __restrict__ vb)
{
    const int bid    = blockIdx.x;
    const int rowblk = bid & 255;
    const int wsel   = bid >> 8;
    unsigned short* outp = (wsel == 0) ? qb : (wsel == 1) ? kb : vb;
    const int m0   = rowblk * 64;
    const int w    = threadIdx.x >> 6;
    const int lane = threadIdx.x & 63;
    const int lr = lane & 15, lg = lane >> 4;
    const int arow = m0 + w * 16 + lr;

    const f32x4 zero = {0.f, 0.f, 0.f, 0.f};
    f32x4 acc[16];
#pragma unroll
    for (int ct = 0; ct < 16; ++ct) acc[ct] = zero;

    for (int ks = 0; ks < 8; ++ks) {
        const float* xp = &x[(size_t)arow * 256 + ks * 32 + lg * 8];
        bf16x8 a = pack8(*(const float4*)xp, *(const float4*)(xp + 4));
        const u16x8* wp = (const u16x8*)(Wp + ((size_t)(wsel * 8 + ks) * 16) * 64 * 8);
#pragma unroll
        for (int ct = 0; ct < 16; ++ct) {
            BFU bb; bb.u = wp[ct * 64 + lane];
            acc[ct] = __builtin_amdgcn_mfma_f32_16x16x32_bf16(a, bb.b, acc[ct], 0, 0, 0);
        }
    }
#pragma unroll
    for (int ct = 0; ct < 16; ++ct)
#pragma unroll
        for (int j = 0; j < 4; ++j)
            outp[(size_t)(m0 + w * 16 + lg * 4 + j) * 256 + ct * 16 + lr] =
                (unsigned short)f2bf(acc[ct][j]);
}

// ---------------------------------------------------------------------------
// Kernel 2 (r16-proven): scores via MFMA, direct bf16 q/k fragment loads.
// Full 64x512 row stripe as four 128-col passes; 33.8KB LDS -> 4 blocks/CU.
// ---------------------------------------------------------------------------
__global__ __launch_bounds__(512) void scores_kernel(
    const unsigned short* __restrict__ qb, const unsigned short* __restrict__ kb,
    const float* __restrict__ res, float* __restrict__ sc_out,
    float* __restrict__ pmax, float* __restrict__ psum)
{
    const int bid  = blockIdx.x;
    const int g    = bid & 255;
    const int st   = bid >> 8;         // 0..7
    const int bf = g >> 3, h = g & 7;
    const size_t sbase = (size_t)g * S_ * S_;
    const int s0 = st * 64;

    __shared__ float T[64][132];
    const int tid = threadIdx.x;
    const int w = tid >> 6, lane = tid & 63;
    const int lr = lane & 15, lg = lane >> 4;

    bf16x8 afrag[4];
#pragma unroll
    for (int rt = 0; rt < 4; ++rt) {
        BFU au;
        au.u = *(const u16x8*)&qb[((size_t)bf * S_ + s0 + rt * 16 + lr) * 256
                                  + h * 32 + lg * 8];
        afrag[rt] = au.b;
    }

    const float scale = 0.17677669529663687f;  // 1/sqrt(32)
    const f32x4 zero = {0.f, 0.f, 0.f, 0.f};

    for (int ch = 0; ch < 4; ++ch) {
        const int c0 = ch * 128;
        __syncthreads();   // T reuse guard

#pragma unroll
        for (int p = 0; p < 4; ++p) {
            int idx = tid + p * 512;
            int r = idx >> 5, c4 = (idx & 31) * 4;
            const f32x4* rp =
                (const f32x4*)&res[sbase + (size_t)(s0 + r) * S_ + c0 + c4];
            *(f32x4*)&T[r][c4] = __builtin_nontemporal_load(rp);
        }
        __syncthreads();

        const int lcol = w * 16 + lr;
        const int tcol = c0 + lcol;
        BFU bu;
        bu.u = *(const u16x8*)&kb[((size_t)bf * S_ + tcol) * 256 + h * 32 + lg * 8];

        f32x4 accr[4];
#pragma unroll
        for (int rt = 0; rt < 4; ++rt)
            accr[rt] = __builtin_amdgcn_mfma_f32_16x16x32_bf16(afrag[rt], bu.b, zero, 0, 0, 0);

        float sc[16];
#pragma unroll
        for (int rt = 0; rt < 4; ++rt)
#pragma unroll
            for (int j = 0; j < 4; ++j) {
                const int r = rt * 16 + lg * 4 + j;
                float v = fmaf(accr[rt][j], scale, T[r][lcol]);
                T[r][lcol] = v;
                sc[rt * 4 + j] = v;
            }
        float m = sc[0];
#pragma unroll
        for (int i = 1; i < 16; ++i) m = fmaxf(m, sc[i]);
        float z = 0.f;
#pragma unroll
        for (int i = 0; i < 16; ++i) z += __expf(sc[i] - m);
#pragma unroll
        for (int off = 16; off <= 32; off <<= 1) {
            float om = __shfl_xor(m, off);
            float oz = __shfl_xor(z, off);
            float nm = fmaxf(m, om);
            z = z * __expf(m - nm) + oz * __expf(om - nm);
            m = nm;
        }
        if (lg == 0) {
            pmax[((size_t)g * 8 + st) * S_ + tcol] = m;
            psum[((size_t)g * 8 + st) * S_ + tcol] = z;
        }
        __syncthreads();

#pragma unroll
        for (int p = 0; p < 4; ++p) {
            int idx = tid + p * 512;
            int r = idx >> 5, c4 = (idx & 31) * 4;
            *(float4*)&sc_out[sbase + (size_t)(s0 + r) * S_ + c0 + c4] =
                *(float4*)&T[r][c4];
        }
    }
}

// ---------------------------------------------------------------------------
// Kernel 3 (proven): merge 8 partial stats -> M, iZ
// ---------------------------------------------------------------------------
__global__ __launch_bounds__(256) void stats_kernel(
    const float* __restrict__ pmax, const float* __restrict__ psum,
    float* __restrict__ M, float* __restrict__ iZ)
{
    const int idx = blockIdx.x * 256 + threadIdx.x;   // g*512 + t
    const int g = idx >> 9;
    const int t = idx & 511;
    float m = -1e30f;
    float pm[8];
#pragma unroll
    for (int i = 0; i < 8; ++i) {
        pm[i] = pmax[((size_t)g * 8 + i) * S_ + t];
        m = fmaxf(m, pm[i]);
    }
    float z = 0.f;
#pragma unroll
    for (int i = 0; i < 8; ++i)
        z += psum[((size_t)g * 8 + i) * S_ + t] * __expf(pm[i] - m);
    M[idx]  = m;
    iZ[idx] = 1.f / z;
}

// ---------------------------------------------------------------------------
// Kernel 4 (r16 + bf16 v in / bf16 ctx out): ctx = attn @ V via bf16 MFMA.
// VT staged from bf16 v (straight copy); ctx written bf16 (its consumer
// rounds to bf16 anyway — numerically identical).
// ---------------------------------------------------------------------------
__global__ __launch_bounds__(256) void pv_kernel(
    const float* __restrict__ sc, const unsigned short* __restrict__ vb,
    const float* __restrict__ M, const float* __restrict__ iZ,
    unsigned short* __restrict__ ctxb)
{
    const int bid = blockIdx.x;
    const int g   = bid & 255;
    const int rt  = 7 - (bid >> 8);
    const int bf = g >> 3, h = g & 7;
    const size_t sbase = (size_t)g * S_ * S_;

    __shared__ unsigned short VT[32][520];   // V^T bf16: VT[vcol][t]
    __shared__ float Ml[S_];
    __shared__ float iZl[S_];
    const int tid = threadIdx.x;

    for (int i = tid; i < S_; i += 256) {
        Ml[i]  = M[(size_t)g * S_ + i];
        iZl[i] = iZ[(size_t)g * S_ + i];
    }
    // stage V^T from bf16 v (no cvt)
    for (int i = tid; i < S_ * 4; i += 256) {
        int t = i >> 2, v8 = (i & 3) * 8;
        u16x8 vv = *(const u16x8*)&vb[((size_t)bf * S_ + t) * 256 + h * 32 + v8];
#pragma unroll
        for (int e = 0; e < 8; ++e) VT[v8 + e][t] = vv[e];
    }
    __syncthreads();

    const int w = tid >> 6, lane = tid & 63;
    const int lr = lane & 15, lg = lane >> 4;
    const int srow = rt * 64 + w * 16 + lr;

    const f32x4 zero = {0.f, 0.f, 0.f, 0.f};
    f32x4 acc[2] = {zero, zero};

    for (int kt = 0; kt < 16; ++kt) {
        const int t0 = kt * 32 + lg * 8;
        const float* sp = &sc[sbase + (size_t)srow * S_ + t0];
        f32x4 sa = __builtin_nontemporal_load((const f32x4*)sp);
        f32x4 sb = __builtin_nontemporal_load((const f32x4*)(sp + 4));
        bf16x8 a;
        a[0] = f2bf(__expf(sa[0] - Ml[t0 + 0]) * iZl[t0 + 0]);
        a[1] = f2bf(__expf(sa[1] - Ml[t0 + 1]) * iZl[t0 + 1]);
        a[2] = f2bf(__expf(sa[2] - Ml[t0 + 2]) * iZl[t0 + 2]);
        a[3] = f2bf(__expf(sa[3] - Ml[t0 + 3]) * iZl[t0 + 3]);
        a[4] = f2bf(__expf(sb[0] - Ml[t0 + 4]) * iZl[t0 + 4]);
        a[5] = f2bf(__expf(sb[1] - Ml[t0 + 5]) * iZl[t0 + 5]);
        a[6] = f2bf(__expf(sb[2] - Ml[t0 + 6]) * iZl[t0 + 6]);
        a[7] = f2bf(__expf(sb[3] - Ml[t0 + 7]) * iZl[t0 + 7]);
#pragma unroll
        for (int ct = 0; ct < 2; ++ct) {
            BFU bb;
            bb.u = *(u16x8*)&VT[ct * 16 + lr][kt * 32 + lg * 8];
            acc[ct] = __builtin_amdgcn_mfma_f32_16x16x32_bf16(a, bb.b, acc[ct], 0, 0, 0);
        }
    }
#pragma unroll
    for (int ct = 0; ct < 2; ++ct)
#pragma unroll
        for (int j = 0; j < 4; ++j)
            ctxb[((size_t)bf * S_ + rt * 64 + w * 16 + lg * 4 + j) * D_
                 + h * 32 + ct * 16 + lr] = (unsigned short)f2bf(acc[ct][j]);
}

// ---------------------------------------------------------------------------
// Kernel 5 (r14-proven fused + bf16 ctx in): out = LayerNorm(ctx @ W_fc + x).
// A fragments load bf16 ctx directly (no cvt).
// ---------------------------------------------------------------------------
__global__ __launch_bounds__(256) void out_kernel(
    const unsigned short* __restrict__ ctxb, const float* __restrict__ x,
    const unsigned short* __restrict__ Wp, const float* __restrict__ gam,
    const float* __restrict__ bet, float* __restrict__ out)
{
    __shared__ float Tl[64][260];
    __shared__ float red[16][4][2];
    const int m0   = blockIdx.x * 64;
    const int tid  = threadIdx.x;
    const int w    = tid >> 6;
    const int lane = tid & 63;
    const int lr = lane & 15, lg = lane >> 4;
    const int arow = m0 + w * 16 + lr;

    const f32x4 zero = {0.f, 0.f, 0.f, 0.f};
    f32x4 acc[16];
#pragma unroll
    for (int ct = 0; ct < 16; ++ct) acc[ct] = zero;

    for (int ks = 0; ks < 8; ++ks) {
        BFU au;
        au.u = *(const u16x8*)&ctxb[(size_t)arow * 256 + ks * 32 + lg * 8];
        const u16x8* wp = (const u16x8*)(Wp + ((size_t)(3 * 8 + ks) * 16) * 64 * 8);
#pragma unroll
        for (int ct = 0; ct < 16; ++ct) {
            BFU bb; bb.u = wp[ct * 64 + lane];
            acc[ct] = __builtin_amdgcn_mfma_f32_16x16x32_bf16(au.b, bb.b, acc[ct], 0, 0, 0);
        }
    }
#pragma unroll
    for (int ct = 0; ct < 16; ++ct)
#pragma unroll
        for (int j = 0; j < 4; ++j)
            Tl[w * 16 + lg * 4 + j][ct * 16 + lr] = acc[ct][j];
    __syncthreads();

    const int j = tid;
    for (int rq = 0; rq < 4; ++rq) {
        if (rq) __syncthreads();
        const int r0 = m0 + rq * 16;
        float y[16];
#pragma unroll
        for (int r = 0; r < 16; ++r)
            y[r] = Tl[rq * 16 + r][j] + x[(size_t)(r0 + r) * D_ + j];

#pragma unroll
        for (int r = 0; r < 16; ++r) {
            float s1 = y[r], s2 = y[r] * y[r];
            for (int off = 32; off; off >>= 1) {
                s1 += __shfl_xor(s1, off);
                s2 += __shfl_xor(s2, off);
            }
            if (lane == 0) { red[r][w][0] = s1; red[r][w][1] = s2; }
        }
        __syncthreads();

#pragma unroll
        for (int r = 0; r < 16; ++r) {
            float s1 = red[r][0][0] + red[r][1][0] + red[r][2][0] + red[r][3][0];
            float s2 = red[r][0][1] + red[r][1][1] + red[r][2][1] + red[r][3][1];
            float mu  = s1 * (1.f / D_);
            float var = s2 * (1.f / D_) - mu * mu;
            float o = (y[r] - mu) * rsqrtf(var + LN_EPS) * gam[j] + bet[j];
            out[(size_t)(r0 + r) * D_ + j] = o;
        }
    }
}

extern "C" void kernel_launch(void* const* d_in, const int* in_sizes, int n_in,
                              void* d_out, int out_size, void* d_ws, size_t ws_size,
                              hipStream_t stream)
{
    const float* x   = (const float*)d_in[0];
    const float* res = (const float*)d_in[1];
    const float* Wq  = (const float*)d_in[2];
    const float* Wk  = (const float*)d_in[3];
    const float* Wv  = (const float*)d_in[4];
    const float* Wfc = (const float*)d_in[5];
    const float* gam = (const float*)d_in[6];
    const float* bet = (const float*)d_in[7];

    float* out    = (float*)d_out;
    float* scores = out + (size_t)NROWS * D_;   // output 1 after output 0

    // ws layout: qb/kb/vb/ctxb bf16 (8 MB each), stats, dedicated Wp.
    unsigned short* qb   = (unsigned short*)d_ws;
    unsigned short* kb   = qb + (size_t)NROWS * 256;
    unsigned short* vb   = kb + (size_t)NROWS * 256;
    unsigned short* ctxb = vb + (size_t)NROWS * 256;
    float* pmax = (float*)(ctxb + (size_t)NROWS * 256);
    float* psum = pmax + (size_t)NG * 8 * S_;
    float* M    = psum + (size_t)NG * 8 * S_;
    float* iZ   = M    + (size_t)NG * S_;
    unsigned short* Wp = (unsigned short*)(iZ + (size_t)NG * S_);  // 0.5 MiB

    wpack_kernel<<<dim3(512), 64, 0, stream>>>(Wq, Wk, Wv, Wfc, Wp);
    qkv_kernel<<<dim3(768), 256, 0, stream>>>(x, Wp, qb, kb, vb);
    scores_kernel<<<dim3(2048), 512, 0, stream>>>(qb, kb, res, scores, pmax, psum);
    stats_kernel<<<dim3(NG * S_ / 256), 256, 0, stream>>>(pmax, psum, M, iZ);
    pv_kernel<<<dim3(2048), 256, 0, stream>>>(scores, vb, M, iZ, ctxb);
    out_kernel<<<dim3(256), 256, 0, stream>>>(ctxb, x, Wp, gam, bet, out);
}

// Round 18
// 256.021 us; speedup vs baseline: 1.0168x; 1.0168x over previous
//
#include <hip/hip_runtime.h>
#include <math.h>

#define B_   8
#define F_   4
#define S_   512
#define D_   256
#define H_   8
#define DK_  32
#define DV_  32
#define NBF  32                 // B*F
#define NROWS (NBF * S_)        // 16384
#define NG   (NBF * H_)         // 256 (b,f,h) groups
#define LN_EPS 1e-5f

typedef __attribute__((ext_vector_type(8))) short bf16x8;
typedef __attribute__((ext_vector_type(4))) float f32x4;
typedef __attribute__((ext_vector_type(8))) unsigned short u16x8;

__device__ __forceinline__ short f2bf(float f) {
    union { float f; unsigned u; } v; v.f = f;
    unsigned u = v.u;
    u += 0x7FFFu + ((u >> 16) & 1u);   // round-to-nearest-even
    return (short)(u >> 16);
}

__device__ __forceinline__ bf16x8 pack8(float4 a, float4 b) {
    bf16x8 r;
    r[0] = f2bf(a.x); r[1] = f2bf(a.y); r[2] = f2bf(a.z); r[3] = f2bf(a.w);
    r[4] = f2bf(b.x); r[5] = f2bf(b.y); r[6] = f2bf(b.z); r[7] = f2bf(b.w);
    return r;
}

union BFU { u16x8 u; bf16x8 b; };

// ---------------------------------------------------------------------------
// Kernel 0 (r10-proven 4-mat): pack Wq,Wk,Wv,Wfc into MFMA B-fragment order.
// ---------------------------------------------------------------------------
__global__ __launch_bounds__(64) void wpack_kernel(
    const float* __restrict__ Wq, const float* __restrict__ Wk,
    const float* __restrict__ Wv, const float* __restrict__ Wfc,
    unsigned short* __restrict__ Wp)
{
    const int bid  = blockIdx.x;           // (wsel*8+ks)*16+ct, 512 blocks
    const int ct   = bid & 15;
    const int ks   = (bid >> 4) & 7;
    const int wsel = bid >> 7;
    const float* W = (wsel == 0) ? Wq : (wsel == 1) ? Wk : (wsel == 2) ? Wv : Wfc;
    const int lane = threadIdx.x;
    const int lr = lane & 15, lg = lane >> 4;
    u16x8 t;
#pragma unroll
    for (int j = 0; j < 8; ++j)
        t[j] = (unsigned short)f2bf(W[(ks * 32 + lg * 8 + j) * 256 + ct * 16 + lr]);
    *(u16x8*)(Wp + ((size_t)bid * 64 + lane) * 8) = t;
}

// ---------------------------------------------------------------------------
// Kernel 1 (r16-proven): q/k written bf16 (producer-side rounding,
// numerically identical); v fp32.
// ---------------------------------------------------------------------------
__global__ __launch_bounds__(256) void qkv_kernel(
    const float* __restrict__ x, const unsigned short* __restrict__ Wp,
    unsigned short* __restrict__ qb, unsigned short* __restrict__ kb,
    float* __restrict__ vo)
{
    const int bid    = blockIdx.x;
    const int rowblk = bid & 255;
    const int wsel   = bid >> 8;
    const int m0   = rowblk * 64;
    const int w    = threadIdx.x >> 6;
    const int lane = threadIdx.x & 63;
    const int lr = lane & 15, lg = lane >> 4;
    const int arow = m0 + w * 16 + lr;

    const f32x4 zero = {0.f, 0.f, 0.f, 0.f};
    f32x4 acc[16];
#pragma unroll
    for (int ct = 0; ct < 16; ++ct) acc[ct] = zero;

    for (int ks = 0; ks < 8; ++ks) {
        const float* xp = &x[(size_t)arow * 256 + ks * 32 + lg * 8];
        bf16x8 a = pack8(*(const float4*)xp, *(const float4*)(xp + 4));
        const u16x8* wp = (const u16x8*)(Wp + ((size_t)(wsel * 8 + ks) * 16) * 64 * 8);
#pragma unroll
        for (int ct = 0; ct < 16; ++ct) {
            BFU bb; bb.u = wp[ct * 64 + lane];
            acc[ct] = __builtin_amdgcn_mfma_f32_16x16x32_bf16(a, bb.b, acc[ct], 0, 0, 0);
        }
    }
    if (wsel < 2) {
        unsigned short* outp = (wsel == 0) ? qb : kb;
#pragma unroll
        for (int ct = 0; ct < 16; ++ct)
#pragma unroll
            for (int j = 0; j < 4; ++j)
                outp[(size_t)(m0 + w * 16 + lg * 4 + j) * 256 + ct * 16 + lr] =
                    (unsigned short)f2bf(acc[ct][j]);
    } else {
#pragma unroll
        for (int ct = 0; ct < 16; ++ct)
#pragma unroll
            for (int j = 0; j < 4; ++j)
                vo[(size_t)(m0 + w * 16 + lg * 4 + j) * 256 + ct * 16 + lr] = acc[ct][j];
    }
}

// ---------------------------------------------------------------------------
// Kernel 2 (r16-proven): scores via MFMA, direct bf16 q/k fragment loads.
// Full 64x512 row stripe as four 128-col passes; 33.8KB LDS -> 4 blocks/CU.
// ---------------------------------------------------------------------------
__global__ __launch_bounds__(512) void scores_kernel(
    const unsigned short* __restrict__ qb, const unsigned short* __restrict__ kb,
    const float* __restrict__ res, float* __restrict__ sc_out,
    float* __restrict__ pmax, float* __restrict__ psum)
{
    const int bid  = blockIdx.x;
    const int g    = bid & 255;
    const int st   = bid >> 8;         // 0..7
    const int bf = g >> 3, h = g & 7;
    const size_t sbase = (size_t)g * S_ * S_;
    const int s0 = st * 64;

    __shared__ float T[64][132];
    const int tid = threadIdx.x;
    const int w = tid >> 6, lane = tid & 63;
    const int lr = lane & 15, lg = lane >> 4;

    bf16x8 afrag[4];
#pragma unroll
    for (int rt = 0; rt < 4; ++rt) {
        BFU au;
        au.u = *(const u16x8*)&qb[((size_t)bf * S_ + s0 + rt * 16 + lr) * 256
                                  + h * 32 + lg * 8];
        afrag[rt] = au.b;
    }

    const float scale = 0.17677669529663687f;  // 1/sqrt(32)
    const f32x4 zero = {0.f, 0.f, 0.f, 0.f};

    for (int ch = 0; ch < 4; ++ch) {
        const int c0 = ch * 128;
        __syncthreads();   // T reuse guard

#pragma unroll
        for (int p = 0; p < 4; ++p) {
            int idx = tid + p * 512;
            int r = idx >> 5, c4 = (idx & 31) * 4;
            const f32x4* rp =
                (const f32x4*)&res[sbase + (size_t)(s0 + r) * S_ + c0 + c4];
            *(f32x4*)&T[r][c4] = __builtin_nontemporal_load(rp);
        }
        __syncthreads();

        const int lcol = w * 16 + lr;
        const int tcol = c0 + lcol;
        BFU bu;
        bu.u = *(const u16x8*)&kb[((size_t)bf * S_ + tcol) * 256 + h * 32 + lg * 8];

        f32x4 accr[4];
#pragma unroll
        for (int rt = 0; rt < 4; ++rt)
            accr[rt] = __builtin_amdgcn_mfma_f32_16x16x32_bf16(afrag[rt], bu.b, zero, 0, 0, 0);

        float sc[16];
#pragma unroll
        for (int rt = 0; rt < 4; ++rt)
#pragma unroll
            for (int j = 0; j < 4; ++j) {
                const int r = rt * 16 + lg * 4 + j;
                float v = fmaf(accr[rt][j], scale, T[r][lcol]);
                T[r][lcol] = v;
                sc[rt * 4 + j] = v;
            }
        float m = sc[0];
#pragma unroll
        for (int i = 1; i < 16; ++i) m = fmaxf(m, sc[i]);
        float z = 0.f;
#pragma unroll
        for (int i = 0; i < 16; ++i) z += __expf(sc[i] - m);
#pragma unroll
        for (int off = 16; off <= 32; off <<= 1) {
            float om = __shfl_xor(m, off);
            float oz = __shfl_xor(z, off);
            float nm = fmaxf(m, om);
            z = z * __expf(m - nm) + oz * __expf(om - nm);
            m = nm;
        }
        if (lg == 0) {
            pmax[((size_t)g * 8 + st) * S_ + tcol] = m;
            psum[((size_t)g * 8 + st) * S_ + tcol] = z;
        }
        __syncthreads();

#pragma unroll
        for (int p = 0; p < 4; ++p) {
            int idx = tid + p * 512;
            int r = idx >> 5, c4 = (idx & 31) * 4;
            *(float4*)&sc_out[sbase + (size_t)(s0 + r) * S_ + c0 + c4] =
                *(float4*)&T[r][c4];
        }
    }
}

// ---------------------------------------------------------------------------
// Kernel 3 (proven): merge 8 partial stats -> M, iZ
// ---------------------------------------------------------------------------
__global__ __launch_bounds__(256) void stats_kernel(
    const float* __restrict__ pmax, const float* __restrict__ psum,
    float* __restrict__ M, float* __restrict__ iZ)
{
    const int idx = blockIdx.x * 256 + threadIdx.x;   // g*512 + t
    const int g = idx >> 9;
    const int t = idx & 511;
    float m = -1e30f;
    float pm[8];
#pragma unroll
    for (int i = 0; i < 8; ++i) {
        pm[i] = pmax[((size_t)g * 8 + i) * S_ + t];
        m = fmaxf(m, pm[i]);
    }
    float z = 0.f;
#pragma unroll
    for (int i = 0; i < 8; ++i)
        z += psum[((size_t)g * 8 + i) * S_ + t] * __expf(pm[i] - m);
    M[idx]  = m;
    iZ[idx] = 1.f / z;
}

// ---------------------------------------------------------------------------
// Kernel 4 (THE change: plain loads for sc re-read — NT hint removed so the
// just-written, L3-resident scores can be served from cache).
// ---------------------------------------------------------------------------
__global__ __launch_bounds__(256) void pv_kernel(
    const float* __restrict__ sc, const float* __restrict__ v,
    const float* __restrict__ M, const float* __restrict__ iZ,
    float* __restrict__ ctx)
{
    const int bid = blockIdx.x;
    const int g   = bid & 255;
    const int rt  = 7 - (bid >> 8);
    const int bf = g >> 3, h = g & 7;
    const size_t sbase = (size_t)g * S_ * S_;

    __shared__ unsigned short VT[32][520];   // V^T bf16: VT[vcol][t]
    __shared__ float Ml[S_];
    __shared__ float iZl[S_];
    const int tid = threadIdx.x;

    for (int i = tid; i < S_; i += 256) {
        Ml[i]  = M[(size_t)g * S_ + i];
        iZl[i] = iZ[(size_t)g * S_ + i];
    }
    for (int i = tid; i < S_ * 8; i += 256) {
        int t = i >> 3, v4 = (i & 7) * 4;
        float4 vv = *(const float4*)&v[((size_t)bf * S_ + t) * D_ + h * 32 + v4];
        VT[v4 + 0][t] = (unsigned short)f2bf(vv.x);
        VT[v4 + 1][t] = (unsigned short)f2bf(vv.y);
        VT[v4 + 2][t] = (unsigned short)f2bf(vv.z);
        VT[v4 + 3][t] = (unsigned short)f2bf(vv.w);
    }
    __syncthreads();

    const int w = tid >> 6, lane = tid & 63;
    const int lr = lane & 15, lg = lane >> 4;
    const int srow = rt * 64 + w * 16 + lr;

    const f32x4 zero = {0.f, 0.f, 0.f, 0.f};
    f32x4 acc[2] = {zero, zero};

    for (int kt = 0; kt < 16; ++kt) {
        const int t0 = kt * 32 + lg * 8;
        const float* sp = &sc[sbase + (size_t)srow * S_ + t0];
        float4 sa = *(const float4*)sp;
        float4 sb = *(const float4*)(sp + 4);
        bf16x8 a;
        a[0] = f2bf(__expf(sa.x - Ml[t0 + 0]) * iZl[t0 + 0]);
        a[1] = f2bf(__expf(sa.y - Ml[t0 + 1]) * iZl[t0 + 1]);
        a[2] = f2bf(__expf(sa.z - Ml[t0 + 2]) * iZl[t0 + 2]);
        a[3] = f2bf(__expf(sa.w - Ml[t0 + 3]) * iZl[t0 + 3]);
        a[4] = f2bf(__expf(sb.x - Ml[t0 + 4]) * iZl[t0 + 4]);
        a[5] = f2bf(__expf(sb.y - Ml[t0 + 5]) * iZl[t0 + 5]);
        a[6] = f2bf(__expf(sb.z - Ml[t0 + 6]) * iZl[t0 + 6]);
        a[7] = f2bf(__expf(sb.w - Ml[t0 + 7]) * iZl[t0 + 7]);
#pragma unroll
        for (int ct = 0; ct < 2; ++ct) {
            BFU bb;
            bb.u = *(u16x8*)&VT[ct * 16 + lr][kt * 32 + lg * 8];
            acc[ct] = __builtin_amdgcn_mfma_f32_16x16x32_bf16(a, bb.b, acc[ct], 0, 0, 0);
        }
    }
#pragma unroll
    for (int ct = 0; ct < 2; ++ct)
#pragma unroll
        for (int j = 0; j < 4; ++j)
            ctx[((size_t)bf * S_ + rt * 64 + w * 16 + lg * 4 + j) * D_
                + h * 32 + ct * 16 + lr] = acc[ct][j];
}

// ---------------------------------------------------------------------------
// Kernel 5 (r14-proven fused): out = LayerNorm(ctx @ W_fc + x).
// ---------------------------------------------------------------------------
__global__ __launch_bounds__(256) void out_kernel(
    const float* __restrict__ ctx, const float* __restrict__ x,
    const unsigned short* __restrict__ Wp, const float* __restrict__ gam,
    const float* __restrict__ bet, float* __restrict__ out)
{
    __shared__ float Tl[64][260];
    __shared__ float red[16][4][2];
    const int m0   = blockIdx.x * 64;
    const int tid  = threadIdx.x;
    const int w    = tid >> 6;
    const int lane = tid & 63;
    const int lr = lane & 15, lg = lane >> 4;
    const int arow = m0 + w * 16 + lr;

    const f32x4 zero = {0.f, 0.f, 0.f, 0.f};
    f32x4 acc[16];
#pragma unroll
    for (int ct = 0; ct < 16; ++ct) acc[ct] = zero;

    for (int ks = 0; ks < 8; ++ks) {
        const float* cp = &ctx[(size_t)arow * 256 + ks * 32 + lg * 8];
        bf16x8 a = pack8(*(const float4*)cp, *(const float4*)(cp + 4));
        const u16x8* wp = (const u16x8*)(Wp + ((size_t)(3 * 8 + ks) * 16) * 64 * 8);
#pragma unroll
        for (int ct = 0; ct < 16; ++ct) {
            BFU bb; bb.u = wp[ct * 64 + lane];
            acc[ct] = __builtin_amdgcn_mfma_f32_16x16x32_bf16(a, bb.b, acc[ct], 0, 0, 0);
        }
    }
#pragma unroll
    for (int ct = 0; ct < 16; ++ct)
#pragma unroll
        for (int j = 0; j < 4; ++j)
            Tl[w * 16 + lg * 4 + j][ct * 16 + lr] = acc[ct][j];
    __syncthreads();

    const int j = tid;
    for (int rq = 0; rq < 4; ++rq) {
        if (rq) __syncthreads();
        const int r0 = m0 + rq * 16;
        float y[16];
#pragma unroll
        for (int r = 0; r < 16; ++r)
            y[r] = Tl[rq * 16 + r][j] + x[(size_t)(r0 + r) * D_ + j];

#pragma unroll
        for (int r = 0; r < 16; ++r) {
            float s1 = y[r], s2 = y[r] * y[r];
            for (int off = 32; off; off >>= 1) {
                s1 += __shfl_xor(s1, off);
                s2 += __shfl_xor(s2, off);
            }
            if (lane == 0) { red[r][w][0] = s1; red[r][w][1] = s2; }
        }
        __syncthreads();

#pragma unroll
        for (int r = 0; r < 16; ++r) {
            float s1 = red[r][0][0] + red[r][1][0] + red[r][2][0] + red[r][3][0];
            float s2 = red[r][0][1] + red[r][1][1] + red[r][2][1] + red[r][3][1];
            float mu  = s1 * (1.f / D_);
            float var = s2 * (1.f / D_) - mu * mu;
            float o = (y[r] - mu) * rsqrtf(var + LN_EPS) * gam[j] + bet[j];
            out[(size_t)(r0 + r) * D_ + j] = o;
        }
    }
}

extern "C" void kernel_launch(void* const* d_in, const int* in_sizes, int n_in,
                              void* d_out, int out_size, void* d_ws, size_t ws_size,
                              hipStream_t stream)
{
    const float* x   = (const float*)d_in[0];
    const float* res = (const float*)d_in[1];
    const float* Wq  = (const float*)d_in[2];
    const float* Wk  = (const float*)d_in[3];
    const float* Wv  = (const float*)d_in[4];
    const float* Wfc = (const float*)d_in[5];
    const float* gam = (const float*)d_in[6];
    const float* bet = (const float*)d_in[7];

    float* out    = (float*)d_out;
    float* scores = out + (size_t)NROWS * D_;   // output 1 after output 0

    // ws layout (r16-proven): qb/kb bf16, v/ctx fp32, stats, dedicated Wp.
    unsigned short* qb = (unsigned short*)d_ws;
    unsigned short* kb = qb + (size_t)NROWS * 256;
    float* v    = (float*)(kb + (size_t)NROWS * 256);
    float* ctx  = v    + (size_t)NROWS * D_;
    float* pmax = ctx  + (size_t)NROWS * D_;
    float* psum = pmax + (size_t)NG * 8 * S_;
    float* M    = psum + (size_t)NG * 8 * S_;
    float* iZ   = M    + (size_t)NG * S_;
    unsigned short* Wp = (unsigned short*)(iZ + (size_t)NG * S_);  // 0.5 MiB

    wpack_kernel<<<dim3(512), 64, 0, stream>>>(Wq, Wk, Wv, Wfc, Wp);
    qkv_kernel<<<dim3(768), 256, 0, stream>>>(x, Wp, qb, kb, v);
    scores_kernel<<<dim3(2048), 512, 0, stream>>>(qb, kb, res, scores, pmax, psum);
    stats_kernel<<<dim3(NG * S_ / 256), 256, 0, stream>>>(pmax, psum, M, iZ);
    pv_kernel<<<dim3(2048), 256, 0, stream>>>(scores, v, M, iZ, ctx);
    out_kernel<<<dim3(256), 256, 0, stream>>>(ctx, x, Wp, gam, bet, out);
}